// Round 15
// baseline (516.606 us; speedup 1.0000x reference)
//
#include <hip/hip_runtime.h>
#include <hip/hip_bf16.h>
#include <math.h>

#define BB 64
#define SS 2048
#define MT (SS*BB)   // 131072 rows of the big GEMM
#define NSTEP 8      // K-steps (K=1024, BK=128)

typedef __attribute__((ext_vector_type(4))) float f4;
typedef __attribute__((ext_vector_type(4))) int   i4;
typedef __attribute__((ext_vector_type(8))) int   i8;

__device__ __forceinline__ float fast_tanh(float x) {
  float t = __expf(2.0f * x);
  return 1.0f - 2.0f * __builtin_amdgcn_rcpf(t + 1.0f);
}

__device__ __forceinline__ f4 mmq(i8 a, i8 b, f4 c) {
  // R8-verified end-to-end (absmax 1.464e-3): MX-fp8, unit scales (0x7F = 2^0)
  return __builtin_amdgcn_mfma_scale_f32_16x16x128_f8f6f4(
      a, b, c, 0, 0, 0, 0x7F7F7F7F, 0, 0x7F7F7F7F);
}

#define GLD16(gp, lp) __builtin_amdgcn_global_load_lds( \
    (const __attribute__((address_space(1))) void*)(gp), \
    (__attribute__((address_space(3))) void*)(lp), 16, 0, 0)
#define WAITV0() asm volatile("s_waitcnt vmcnt(0)" ::: "memory")
#define BAR()    __builtin_amdgcn_s_barrier()
#define SCHED0() __builtin_amdgcn_sched_barrier(0)

// ---- coalesced pack: f32 (rows x stride) -> swizzled fp8 e4m3 units.
// Global layout: [panel(256 rows)][kt 0..7][h=row>>7][r=row&127][8 slots x 16B]
// phys slot sp at row r holds source cols kt*128 + ((sp^(r&7))*16 ..+16).
// grid: (rows/64, 4); block 256.
__global__ void k_packq(const float* __restrict__ src, unsigned char* __restrict__ dst,
                        int stride) {
  __shared__ float ls[64][260];
  int g = blockIdx.x, cb = blockIdx.y, tid = threadIdx.x;
  int cl = (tid & 63) * 4, rbk = tid >> 6;
  const float* s0 = src + (size_t)(g * 64) * stride + cb * 256 + cl;
  #pragma unroll
  for (int it = 0; it < 16; ++it) {
    int rr = it * 4 + rbk;
    *(f4*)&ls[rr][cl] = *(const f4*)(s0 + (size_t)rr * stride);
  }
  __syncthreads();
  int rr = tid & 63;
  int q = tid >> 6;                 // 0..3: 64-col chunk
  int kt = cb * 2 + (q >> 1);
  int grow = g * 64 + rr;
  int panel = grow >> 8, pr = grow & 255, h = pr >> 7, r = pr & 127;
  int rx = r & 7;
  unsigned char* ub = dst + (((size_t)(panel * 8 + kt) * 2 + h) * 128 + r) * 128;
  #pragma unroll
  for (int si = 0; si < 4; ++si) {
    int s = (q & 1) * 4 + si;               // logical 16B slot within the 128-col kstep
    int sp = s ^ rx;                        // inverse-swizzled physical slot
    const float* fp = &ls[rr][q * 64 + si * 16];
    i4 w;
    #pragma unroll
    for (int k = 0; k < 4; ++k) {
      int b = 0;
      b = __builtin_amdgcn_cvt_pk_fp8_f32(fp[k * 4 + 0], fp[k * 4 + 1], b, 0);
      b = __builtin_amdgcn_cvt_pk_fp8_f32(fp[k * 4 + 2], fp[k * 4 + 3], b, 1);
      w[k] = b;
    }
    *(i4*)(ub + sp * 16) = w;
  }
}

// ---- hp[b][a] = hidden[b,:]·Wd[a,:] + bias[a]
__global__ void k_hp(const float* __restrict__ hidden, const float* __restrict__ w,
                     const float* __restrict__ wbias, float* __restrict__ hp) {
  __shared__ float hs[1024];
  int b = blockIdx.x, tid = threadIdx.x;
  for (int i = tid; i < 1024; i += 256) hs[i] = hidden[b * 1024 + i];
  __syncthreads();
  int a = blockIdx.y * 256 + tid;
  const f4* wd = (const f4*)(w + a * 2048 + 1024);
  const f4* hv = (const f4*)hs;
  float acc = wbias[a];
  #pragma unroll 8
  for (int d = 0; d < 256; ++d) {
    f4 x = wd[d], y = hv[d];
    acc += x[0]*y[0] + x[1]*y[1] + x[2]*y[2] + x[3]*y[3];
  }
  hp[b * 1024 + a] = acc;
}

// ---- fused GEMM, MX-fp8 (unit scales, 16x16x128): 128x128 tile, BK=128,
// 8 waves (2M x 4N), per-wave 64x32. Register budget ~100 < 128 cap at
// launch_bounds(512,4) -> 2 blocks/CU, no spill (R8/R9's failure mode).
// Ring-2 LDS 64KB; 4 GLD16/step; lead-1 + vmcnt(0)+BAR boundary (R13-proven).
// partials[p][b][s], p = bn*4 + wc (32 partials).
__global__ __launch_bounds__(512, 4) void k_gemm(
    const unsigned char* __restrict__ Aq, const unsigned char* __restrict__ Wq,
    const float* __restrict__ hp, const float* __restrict__ vw,
    float* __restrict__ part, int bm0, int nbm) {
  extern __shared__ char smem[];
  int bid = blockIdx.x;
  int nwg = nbm * 8;
  int cpx = nwg >> 3;
  int wg = (bid & 7) * cpx + (bid >> 3);   // bijective (nwg % 8 == 0)
  int bn = wg & 7;              // bn fastest: 8 readers of one A-tile on one XCD
  int bmL = wg >> 3;
  int tid = threadIdx.x, lane = tid & 63;
  int wid = tid >> 6, wr = wid >> 2, wc = wid & 3;
  int c = lane & 15, kq = lane >> 4;

  // R8-verified fragment addressing: 128B rows, slot (2kq)^(row&7), pair = ^16
  int sx0 = ((2 * kq) ^ (c & 7)) << 4;
  int sx1 = sx0 ^ 16;
  int aoff = (wr * 64 + c) * 128;           // + mi*2048 + sx
  int boff = 16384 + (wc * 32 + c) * 128;   // + ni*2048 + sx

  // staging: vq layout == LDS layout -> linear tid*16 on both sides
  const unsigned char* aS0 = Aq + (size_t)(bmL >> 1) * 262144 + (bmL & 1) * 16384 + tid * 16;
  const unsigned char* bS0 = Wq + (size_t)(bn >> 1) * 262144 + (bn & 1) * 16384 + tid * 16;
  auto stage = [&](int kt) {
    char* d = smem + (kt & 1) * 32768 + tid * 16;
    const unsigned char* as_ = aS0 + (size_t)kt * 32768;
    const unsigned char* bs_ = bS0 + (size_t)kt * 32768;
    GLD16(as_, d);
    GLD16(as_ + 8192, d + 8192);
    GLD16(bs_, d + 16384);
    GLD16(bs_ + 8192, d + 24576);
  };

  f4 acc[4][2];
  f4 z = {0.f, 0.f, 0.f, 0.f};
  #pragma unroll
  for (int i = 0; i < 4; ++i) { acc[i][0] = z; acc[i][1] = z; }

  i8 a0, a1, a2, a3, b0, b1;

#define LD2(DST, ADDR) { \
    i4 lo_ = *(const i4*)((ADDR) + sx0); \
    i4 hi_ = *(const i4*)((ADDR) + sx1); \
    DST = __builtin_shufflevector(lo_, hi_, 0, 1, 2, 3, 4, 5, 6, 7); }

  // prologue
  stage(0);
  WAITV0();
  SCHED0(); BAR(); SCHED0();

  #pragma unroll 1
  for (int t = 0; t < NSTEP; ++t) {
    const char* rb = smem + (t & 1) * 32768;
    if (t < NSTEP - 1) stage(t + 1);
    const char* ap = rb + aoff;
    const char* bp = rb + boff;
    LD2(a0, ap);  LD2(a1, ap + 2048);  LD2(a2, ap + 4096);  LD2(a3, ap + 6144);
    LD2(b0, bp);  LD2(b1, bp + 2048);
    __builtin_amdgcn_s_setprio(1);
    acc[0][0] = mmq(a0, b0, acc[0][0]);  acc[0][1] = mmq(a0, b1, acc[0][1]);
    acc[1][0] = mmq(a1, b0, acc[1][0]);  acc[1][1] = mmq(a1, b1, acc[1][1]);
    acc[2][0] = mmq(a2, b0, acc[2][0]);  acc[2][1] = mmq(a2, b1, acc[2][1]);
    acc[3][0] = mmq(a3, b0, acc[3][0]);  acc[3][1] = mmq(a3, b1, acc[3][1]);
    __builtin_amdgcn_s_setprio(0);
    if (t < NSTEP - 1) {
      WAITV0();               // stage(t+1)'s 4 loads issued a full step back
      SCHED0(); BAR(); SCHED0();
    }
  }
#undef LD2

  // ---- epilogue: stage hp[b][bn*128..+127] (64x128 f32 = 32KB) into LDS
  __syncthreads();
  {
    const float* hprow = hp + bn * 128;
    float* lhp = (float*)smem;
    #pragma unroll
    for (int qd = 0; qd < 4; ++qd) {
      int i = qd * 512 + tid;
      int b = i >> 5, col4 = i & 31;
      *(f4*)(lhp + b * 128 + col4 * 4) = *(const f4*)(hprow + (size_t)b * 1024 + col4 * 4);
    }
  }
  __syncthreads();
  const float* lhpf = (const float*)smem;

  int lg = kq;
  int bm = bm0 + bmL;
  float rs[4][4];
  #pragma unroll
  for (int mi = 0; mi < 4; ++mi)
    #pragma unroll
    for (int j = 0; j < 4; ++j) rs[mi][j] = 0.f;
  #pragma unroll
  for (int ni = 0; ni < 2; ++ni) {
    int colL = wc * 32 + ni * 16 + c;
    float vwa = vw[bn * 128 + colL];
    #pragma unroll
    for (int mi = 0; mi < 4; ++mi) {
      #pragma unroll
      for (int j = 0; j < 4; ++j) {
        int r = wr * 64 + mi * 16 + lg * 4 + j;
        int b = r & 63;
        float x = acc[mi][ni][j] + lhpf[b * 128 + colL];
        rs[mi][j] += fast_tanh(x) * vwa;
      }
    }
  }
  #pragma unroll
  for (int off = 1; off < 16; off <<= 1) {
    #pragma unroll
    for (int mi = 0; mi < 4; ++mi)
      #pragma unroll
      for (int j = 0; j < 4; ++j)
        rs[mi][j] += __shfl_xor(rs[mi][j], off, 64);
  }
  if (c == 0) {
    int p = bn * 4 + wc;
    #pragma unroll
    for (int mi = 0; mi < 4; ++mi)
      #pragma unroll
      for (int j = 0; j < 4; ++j) {
        int m = bm * 128 + wr * 64 + mi * 16 + lg * 4 + j;
        int b = m & 63, s = m >> 6;
        part[(size_t)p * MT + b * SS + s] = rs[mi][j];
      }
  }
}

// ---- sum 32 partials -> scores, softmax over s per b -> weights[b][s]
__global__ void k_softmax(const float* __restrict__ part, float* __restrict__ wt) {
  int b = blockIdx.x, tid = threadIdx.x, lane = tid & 63, wid = tid >> 6;
  __shared__ float red[8];
  float sc[8];
  float mx = -1e30f;
  #pragma unroll
  for (int i = 0; i < 8; ++i) {
    int s = tid + i * 256;
    float a = 0.f;
    #pragma unroll
    for (int p = 0; p < 32; ++p) a += part[(size_t)p * MT + b * SS + s];
    sc[i] = a; mx = fmaxf(mx, a);
  }
  for (int o = 1; o < 64; o <<= 1) mx = fmaxf(mx, __shfl_xor(mx, o, 64));
  if (lane == 0) red[wid] = mx;
  __syncthreads();
  mx = fmaxf(fmaxf(red[0], red[1]), fmaxf(red[2], red[3]));
  float sum = 0.f;
  #pragma unroll
  for (int i = 0; i < 8; ++i) { sc[i] = expf(sc[i] - mx); sum += sc[i]; }
  for (int o = 1; o < 64; o <<= 1) sum += __shfl_xor(sum, o, 64);
  if (lane == 0) red[4 + wid] = sum;
  __syncthreads();
  sum = red[4] + red[5] + red[6] + red[7];
  float inv = 1.f / sum;
  #pragma unroll
  for (int i = 0; i < 8; ++i) wt[b * SS + tid + i * 256] = sc[i] * inv;
}

// ---- context from f32 v: ctxp[cch][b][e] = sum_{s in chunk} w[b][s]*v[s][b][e]
__global__ void k_ctx_f32(const float* __restrict__ v, const float* __restrict__ wt,
                          float* __restrict__ ctxp) {
  int b = blockIdx.x, cch = blockIdx.y, tid = threadIdx.x;
  f4 acc = {0.f, 0.f, 0.f, 0.f};
  int s0 = cch * 128;
  const float* wrow = wt + b * SS;
  #pragma unroll 4
  for (int s = s0; s < s0 + 128; ++s) {
    float ws = wrow[s];
    const f4* vp = (const f4*)(v + (size_t)(s * 64 + b) * 1024);
    acc += vp[tid] * ws;
  }
  *(f4*)(ctxp + (size_t)(cch * 64 + b) * 1024 + tid * 4) = acc;
}

__global__ void k_out(const float* __restrict__ ctxp, float* __restrict__ out) {
  int b = blockIdx.x, tid = threadIdx.x;
  f4 acc = {0.f, 0.f, 0.f, 0.f};
  #pragma unroll
  for (int cch = 0; cch < 16; ++cch)
    acc += *(const f4*)(ctxp + (size_t)(cch * 64 + b) * 1024 + tid * 4);
  *(f4*)(out + b * 1024 + tid * 4) = acc;
}

extern "C" void kernel_launch(void* const* d_in, const int* in_sizes, int n_in,
                              void* d_out, int out_size, void* d_ws, size_t ws_size,
                              hipStream_t stream) {
  const float* hidden = (const float*)d_in[0];
  const float* v      = (const float*)d_in[1];   // (S, B, ENC) rows s*64+b
  const float* ww     = (const float*)d_in[2];   // (1024, 2048)
  const float* wbias  = (const float*)d_in[3];   // (1024)
  const float* vwgt   = (const float*)d_in[4];   // (1, 1024)
  float* out = (float*)d_out;

  char* ws = (char*)d_ws;
  float*          hp   = (float*)(ws);                                    // 256 KB
  unsigned char*  wq   = (unsigned char*)(ws + 262144);                   // 1 MB fp8 We
  float*          part = (float*)(ws + 262144 + 1048576);                 // 16 MB (32 partials)
  float*          wt   = (float*)(ws + 262144 + 1048576 + 16777216);      // 512 KB
  float*          ctxp = (float*)(ws + 262144 + 1048576 + 16777216 + 524288); // 4 MB
  size_t fixed = 262144 + 1048576 + 16777216 + 524288 + 4194304;
  unsigned char*  vq   = (unsigned char*)(ws + fixed);                    // 128 MB fp8 v

  size_t avail = (ws_size > fixed) ? (ws_size - fixed) : 0;
  long rows_chunk = (long)(avail / 1024) & ~511L;      // fp8 row = 1024 B
  if (rows_chunk > MT) rows_chunk = MT;
  if (rows_chunk < 512) rows_chunk = 512;

  hipFuncSetAttribute((const void*)k_gemm, hipFuncAttributeMaxDynamicSharedMemorySize, 65536);

  k_packq<<<dim3(16, 4), 256, 0, stream>>>(ww, wq, 2048);
  k_hp<<<dim3(64, 4), 256, 0, stream>>>(hidden, ww, wbias, hp);

  for (long r0 = 0; r0 < MT; r0 += rows_chunk) {
    long nr = MT - r0; if (nr > rows_chunk) nr = rows_chunk;
    int nbm = (int)(nr / 128);
    k_packq<<<dim3((int)(nr / 64), 4), 256, 0, stream>>>(v + (size_t)r0 * 1024, vq, 1024);
    k_gemm<<<nbm * 8, 512, 65536, stream>>>(vq, wq, hp, vwgt, part, (int)(r0 / 128), nbm);
  }

  k_softmax<<<64, 256, 0, stream>>>(part, wt);
  k_ctx_f32<<<dim3(64, 16), 256, 0, stream>>>(v, wt, ctxp);
  k_out<<<64, 256, 0, stream>>>(ctxp, out);
}

// Round 16
// 498.729 us; speedup vs baseline: 1.0358x; 1.0358x over previous
//
#include <hip/hip_runtime.h>
#include <hip/hip_bf16.h>
#include <math.h>

#define BB 64
#define SS 2048
#define MT (SS*BB)   // 131072 rows of the big GEMM
#define NSTEP 16     // K-steps (K=1024, BK=64)

typedef __attribute__((ext_vector_type(4))) float f4;
typedef __attribute__((ext_vector_type(4))) int   i4;

__device__ __forceinline__ float fast_tanh(float x) {
  float t = __expf(2.0f * x);
  return 1.0f - 2.0f * __builtin_amdgcn_rcpf(t + 1.0f);
}

#define GLD16(gp, lp) __builtin_amdgcn_global_load_lds( \
    (const __attribute__((address_space(1))) void*)(gp), \
    (__attribute__((address_space(3))) void*)(lp), 16, 0, 0)
#define WAITV0() asm volatile("s_waitcnt vmcnt(0)" ::: "memory")
#define BAR()    __builtin_amdgcn_s_barrier()
#define SCHED0() __builtin_amdgcn_sched_barrier(0)

// ---- coalesced pack: f32 (rows x stride) -> swizzled fp8 e4m3 units.
// Global layout: [panel(256 rows)][kt 0..7][h=row>>7][r=row&127][8 slots x 16B]
// phys slot sp at row r holds source cols kt*128 + ((sp^(r&7))*16 ..+16).
// grid: (rows/64, 4); block 256.
__global__ void k_packq(const float* __restrict__ src, unsigned char* __restrict__ dst,
                        int stride) {
  __shared__ float ls[64][260];
  int g = blockIdx.x, cb = blockIdx.y, tid = threadIdx.x;
  int cl = (tid & 63) * 4, rbk = tid >> 6;
  const float* s0 = src + (size_t)(g * 64) * stride + cb * 256 + cl;
  #pragma unroll
  for (int it = 0; it < 16; ++it) {
    int rr = it * 4 + rbk;
    *(f4*)&ls[rr][cl] = *(const f4*)(s0 + (size_t)rr * stride);
  }
  __syncthreads();
  int rr = tid & 63;
  int q = tid >> 6;                 // 0..3: 64-col chunk
  int kt = cb * 2 + (q >> 1);
  int grow = g * 64 + rr;
  int panel = grow >> 8, pr = grow & 255, h = pr >> 7, r = pr & 127;
  int rx = r & 7;
  unsigned char* ub = dst + (((size_t)(panel * 8 + kt) * 2 + h) * 128 + r) * 128;
  #pragma unroll
  for (int si = 0; si < 4; ++si) {
    int s = (q & 1) * 4 + si;               // logical 16B slot within the 128-col kstep
    int sp = s ^ rx;                        // inverse-swizzled physical slot
    const float* fp = &ls[rr][q * 64 + si * 16];
    i4 w;
    #pragma unroll
    for (int k = 0; k < 4; ++k) {
      int b = 0;
      b = __builtin_amdgcn_cvt_pk_fp8_f32(fp[k * 4 + 0], fp[k * 4 + 1], b, 0);
      b = __builtin_amdgcn_cvt_pk_fp8_f32(fp[k * 4 + 2], fp[k * 4 + 3], b, 1);
      w[k] = b;
    }
    *(i4*)(ub + sp * 16) = w;
  }
}

// ---- hp[b][a] = hidden[b,:]·Wd[a,:] + bias[a]
__global__ void k_hp(const float* __restrict__ hidden, const float* __restrict__ w,
                     const float* __restrict__ wbias, float* __restrict__ hp) {
  __shared__ float hs[1024];
  int b = blockIdx.x, tid = threadIdx.x;
  for (int i = tid; i < 1024; i += 256) hs[i] = hidden[b * 1024 + i];
  __syncthreads();
  int a = blockIdx.y * 256 + tid;
  const f4* wd = (const f4*)(w + a * 2048 + 1024);
  const f4* hv = (const f4*)hs;
  float acc = wbias[a];
  #pragma unroll 8
  for (int d = 0; d < 256; ++d) {
    f4 x = wd[d], y = hv[d];
    acc += x[0]*y[0] + x[1]*y[1] + x[2]*y[2] + x[3]*y[3];
  }
  hp[b * 1024 + a] = acc;
}

// ---- fused GEMM, fp8 e4m3, 2 blocks/CU: 256x128 tile, BK=64, 8 waves (4M x 2N),
// per-wave 64x64. LDS 48KB (2 buf x {A 16KB, B 8KB}). 64B LDS rows: bank =
// (16c + 4*slot') mod 32 -> conflict-free XOR is ((row>>1)&3), NOT (row&3)
// (R12's (c&3) cost 1.05e8 conflict-cycles; R13's fix removed them).
// partials[p][b][s], p = bn*2 + wc.
__global__ __launch_bounds__(512, 4) void k_gemm(
    const unsigned char* __restrict__ Aq, const unsigned char* __restrict__ Wq,
    const float* __restrict__ hp, const float* __restrict__ vw,
    float* __restrict__ part, int bm0, int nbm) {
  extern __shared__ char smem[];
  int bid = blockIdx.x;
  int nwg = nbm * 8;
  int cpx = nwg >> 3;
  int wg = (bid & 7) * cpx + (bid >> 3);   // bijective (nwg % 8 == 0)
  int bn = wg & 7;              // bn fastest: 8 readers of one A-tile on one XCD
  int bmL = wg >> 3;
  int tid = threadIdx.x, lane = tid & 63;
  int wid = tid >> 6, wr = wid >> 1, wc = wid & 1;
  int c = lane & 15, kq = lane >> 4;

  // fragment LDS byte offsets (64B rows, 4 slots, XOR-((c>>1)&3) swizzle)
  int csw = (c >> 1) & 3;
  int sxf0 = ((((kq >> 1)    ) ^ csw) << 4) + ((kq & 1) << 3);  // ks0 (k 0..31)
  int sxf1 = ((((kq >> 1) + 2) ^ csw) << 4) + ((kq & 1) << 3);  // ks1 (k 32..63)
  int aoff = (wr * 64 + c) * 64;            // + mi*1024 + sxf
  int boff = 16384 + (wc * 64 + c) * 64;    // + ni*1024 + sxf

  // staging addresses: thread -> (r = tid>>2, j = tid&3); LDS phys slot j at
  // row r holds logical slot j ^ ((r>>1)&3); global phys = logical ^ (r&7)
  int rA = tid >> 2, jA = tid & 3;
  int jsw = jA ^ ((rA >> 1) & 3);
  int aco0 = (((jsw    ) ^ (rA & 7)) << 4);   // kh=0 source slot bytes
  int aco1 = (((jsw + 4) ^ (rA & 7)) << 4);   // kh=1
  const unsigned char* aU = Aq + (size_t)bmL * 262144 + rA * 128;
  const unsigned char* bU = Wq + (size_t)(bn >> 1) * 262144 + (bn & 1) * 16384 + rA * 128;

  auto stage = [&](int tt) {
    int kt = tt >> 1;
    int co = (tt & 1) ? aco1 : aco0;
    char* dst = smem + (tt & 1) * 24576 + tid * 16;
    const unsigned char* as_ = aU + kt * 32768 + co;
    const unsigned char* bs_ = bU + kt * 32768 + co;
    GLD16(as_, dst);                    // A rows 0..127
    GLD16(as_ + 16384, dst + 8192);     // A rows 128..255 (h=1)
    GLD16(bs_, dst + 16384);            // B rows 0..127
  };

  f4 acc[4][4];
  f4 z = {0.f, 0.f, 0.f, 0.f};
  #pragma unroll
  for (int i = 0; i < 4; ++i)
    #pragma unroll
    for (int j = 0; j < 4; ++j) acc[i][j] = z;

#define MMK(SX) { \
    const char* ap_ = rb + aoff + (SX); \
    const char* bp_ = rb + boff + (SX); \
    long a0_ = *(const long*)(ap_);        long a1_ = *(const long*)(ap_ + 1024); \
    long a2_ = *(const long*)(ap_ + 2048); long a3_ = *(const long*)(ap_ + 3072); \
    long b0_ = *(const long*)(bp_);        long b1_ = *(const long*)(bp_ + 1024); \
    long b2_ = *(const long*)(bp_ + 2048); long b3_ = *(const long*)(bp_ + 3072); \
    __builtin_amdgcn_s_setprio(1); \
    acc[0][0] = __builtin_amdgcn_mfma_f32_16x16x32_fp8_fp8(a0_, b0_, acc[0][0], 0, 0, 0); \
    acc[0][1] = __builtin_amdgcn_mfma_f32_16x16x32_fp8_fp8(a0_, b1_, acc[0][1], 0, 0, 0); \
    acc[0][2] = __builtin_amdgcn_mfma_f32_16x16x32_fp8_fp8(a0_, b2_, acc[0][2], 0, 0, 0); \
    acc[0][3] = __builtin_amdgcn_mfma_f32_16x16x32_fp8_fp8(a0_, b3_, acc[0][3], 0, 0, 0); \
    acc[1][0] = __builtin_amdgcn_mfma_f32_16x16x32_fp8_fp8(a1_, b0_, acc[1][0], 0, 0, 0); \
    acc[1][1] = __builtin_amdgcn_mfma_f32_16x16x32_fp8_fp8(a1_, b1_, acc[1][1], 0, 0, 0); \
    acc[1][2] = __builtin_amdgcn_mfma_f32_16x16x32_fp8_fp8(a1_, b2_, acc[1][2], 0, 0, 0); \
    acc[1][3] = __builtin_amdgcn_mfma_f32_16x16x32_fp8_fp8(a1_, b3_, acc[1][3], 0, 0, 0); \
    acc[2][0] = __builtin_amdgcn_mfma_f32_16x16x32_fp8_fp8(a2_, b0_, acc[2][0], 0, 0, 0); \
    acc[2][1] = __builtin_amdgcn_mfma_f32_16x16x32_fp8_fp8(a2_, b1_, acc[2][1], 0, 0, 0); \
    acc[2][2] = __builtin_amdgcn_mfma_f32_16x16x32_fp8_fp8(a2_, b2_, acc[2][2], 0, 0, 0); \
    acc[2][3] = __builtin_amdgcn_mfma_f32_16x16x32_fp8_fp8(a2_, b3_, acc[2][3], 0, 0, 0); \
    acc[3][0] = __builtin_amdgcn_mfma_f32_16x16x32_fp8_fp8(a3_, b0_, acc[3][0], 0, 0, 0); \
    acc[3][1] = __builtin_amdgcn_mfma_f32_16x16x32_fp8_fp8(a3_, b1_, acc[3][1], 0, 0, 0); \
    acc[3][2] = __builtin_amdgcn_mfma_f32_16x16x32_fp8_fp8(a3_, b2_, acc[3][2], 0, 0, 0); \
    acc[3][3] = __builtin_amdgcn_mfma_f32_16x16x32_fp8_fp8(a3_, b3_, acc[3][3], 0, 0, 0); \
    __builtin_amdgcn_s_setprio(0); }

  // prologue: stage step 0, drain, barrier
  stage(0);
  WAITV0();
  SCHED0(); BAR(); SCHED0();

  #pragma unroll 1
  for (int t = 0; t < NSTEP; ++t) {
    const char* rb = smem + (t & 1) * 24576;
    if (t < NSTEP - 1) stage(t + 1);
    MMK(sxf0);
    MMK(sxf1);
    if (t < NSTEP - 1) {
      WAITV0();             // t+1's 3 loads issued a full step ago -> cheap drain
      SCHED0(); BAR(); SCHED0();
    }
  }
#undef MMK

  // ---- epilogue: stage hp[b][bn*128..+128] (64x128 f32 = 32KB) into LDS
  __syncthreads();
  {
    const float* hprow = hp + bn * 128;
    float* lhp = (float*)smem;
    #pragma unroll
    for (int qd = 0; qd < 4; ++qd) {
      int i = qd * 512 + tid;
      int b = i >> 5, col4 = i & 31;
      *(f4*)(lhp + b * 128 + col4 * 4) = *(const f4*)(hprow + (size_t)b * 1024 + col4 * 4);
    }
  }
  __syncthreads();
  const float* lhpf = (const float*)smem;

  int lg = kq;
  int bm = bm0 + bmL;
  float rs[4][4];
  #pragma unroll
  for (int mi = 0; mi < 4; ++mi)
    #pragma unroll
    for (int j = 0; j < 4; ++j) rs[mi][j] = 0.f;
  #pragma unroll
  for (int ni = 0; ni < 4; ++ni) {
    int colL = wc * 64 + ni * 16 + c;
    float vwa = vw[bn * 128 + colL];
    #pragma unroll
    for (int mi = 0; mi < 4; ++mi) {
      #pragma unroll
      for (int j = 0; j < 4; ++j) {
        int r = wr * 64 + mi * 16 + lg * 4 + j;
        int b = r & 63;
        float x = acc[mi][ni][j] + lhpf[b * 128 + colL];
        rs[mi][j] += fast_tanh(x) * vwa;
      }
    }
  }
  #pragma unroll
  for (int off = 1; off < 16; off <<= 1) {
    #pragma unroll
    for (int mi = 0; mi < 4; ++mi)
      #pragma unroll
      for (int j = 0; j < 4; ++j)
        rs[mi][j] += __shfl_xor(rs[mi][j], off, 64);
  }
  if (c == 0) {
    int p = bn * 2 + wc;
    #pragma unroll
    for (int mi = 0; mi < 4; ++mi)
      #pragma unroll
      for (int j = 0; j < 4; ++j) {
        int m = bm * 256 + wr * 64 + mi * 16 + lg * 4 + j;
        int b = m & 63, s = m >> 6;
        part[(size_t)p * MT + b * SS + s] = rs[mi][j];
      }
  }
}

// ---- sum 16 partials -> scores, softmax over s per b -> weights[b][s]
__global__ void k_softmax(const float* __restrict__ part, float* __restrict__ wt) {
  int b = blockIdx.x, tid = threadIdx.x, lane = tid & 63, wid = tid >> 6;
  __shared__ float red[8];
  float sc[8];
  float mx = -1e30f;
  #pragma unroll
  for (int i = 0; i < 8; ++i) {
    int s = tid + i * 256;
    float a = 0.f;
    #pragma unroll
    for (int p = 0; p < 16; ++p) a += part[(size_t)p * MT + b * SS + s];
    sc[i] = a; mx = fmaxf(mx, a);
  }
  for (int o = 1; o < 64; o <<= 1) mx = fmaxf(mx, __shfl_xor(mx, o, 64));
  if (lane == 0) red[wid] = mx;
  __syncthreads();
  mx = fmaxf(fmaxf(red[0], red[1]), fmaxf(red[2], red[3]));
  float sum = 0.f;
  #pragma unroll
  for (int i = 0; i < 8; ++i) { sc[i] = expf(sc[i] - mx); sum += sc[i]; }
  for (int o = 1; o < 64; o <<= 1) sum += __shfl_xor(sum, o, 64);
  if (lane == 0) red[4 + wid] = sum;
  __syncthreads();
  sum = red[4] + red[5] + red[6] + red[7];
  float inv = 1.f / sum;
  #pragma unroll
  for (int i = 0; i < 8; ++i) wt[b * SS + tid + i * 256] = sc[i] * inv;
}

// ---- context from f32 v: ctxp[cch][b][e] = sum_{s in chunk} w[b][s]*v[s][b][e]
__global__ void k_ctx_f32(const float* __restrict__ v, const float* __restrict__ wt,
                          float* __restrict__ ctxp) {
  int b = blockIdx.x, cch = blockIdx.y, tid = threadIdx.x;
  f4 acc = {0.f, 0.f, 0.f, 0.f};
  int s0 = cch * 128;
  const float* wrow = wt + b * SS;
  #pragma unroll 4
  for (int s = s0; s < s0 + 128; ++s) {
    float ws = wrow[s];
    const f4* vp = (const f4*)(v + (size_t)(s * 64 + b) * 1024);
    acc += vp[tid] * ws;
  }
  *(f4*)(ctxp + (size_t)(cch * 64 + b) * 1024 + tid * 4) = acc;
}

__global__ void k_out(const float* __restrict__ ctxp, float* __restrict__ out) {
  int b = blockIdx.x, tid = threadIdx.x;
  f4 acc = {0.f, 0.f, 0.f, 0.f};
  #pragma unroll
  for (int cch = 0; cch < 16; ++cch)
    acc += *(const f4*)(ctxp + (size_t)(cch * 64 + b) * 1024 + tid * 4);
  *(f4*)(out + b * 1024 + tid * 4) = acc;
}

extern "C" void kernel_launch(void* const* d_in, const int* in_sizes, int n_in,
                              void* d_out, int out_size, void* d_ws, size_t ws_size,
                              hipStream_t stream) {
  const float* hidden = (const float*)d_in[0];
  const float* v      = (const float*)d_in[1];   // (S, B, ENC) rows s*64+b
  const float* ww     = (const float*)d_in[2];   // (1024, 2048)
  const float* wbias  = (const float*)d_in[3];   // (1024)
  const float* vwgt   = (const float*)d_in[4];   // (1, 1024)
  float* out = (float*)d_out;

  char* ws = (char*)d_ws;
  float*          hp   = (float*)(ws);                                   // 256 KB
  unsigned char*  wq   = (unsigned char*)(ws + 262144);                  // 1 MB fp8 We
  float*          part = (float*)(ws + 262144 + 1048576);                // 8 MB
  float*          wt   = (float*)(ws + 262144 + 1048576 + 8388608);      // 512 KB
  float*          ctxp = (float*)(ws + 262144 + 1048576 + 8388608 + 524288); // 4 MB
  size_t fixed = 262144 + 1048576 + 8388608 + 524288 + 4194304;
  unsigned char*  vq   = (unsigned char*)(ws + fixed);                   // 128 MB fp8 v

  size_t avail = (ws_size > fixed) ? (ws_size - fixed) : 0;
  long rows_chunk = (long)(avail / 1024) & ~511L;      // fp8 row = 1024 B
  if (rows_chunk > MT) rows_chunk = MT;
  if (rows_chunk < 512) rows_chunk = 512;

  hipFuncSetAttribute((const void*)k_gemm, hipFuncAttributeMaxDynamicSharedMemorySize, 49152);

  k_packq<<<dim3(16, 4), 256, 0, stream>>>(ww, wq, 2048);
  k_hp<<<dim3(64, 4), 256, 0, stream>>>(hidden, ww, wbias, hp);

  for (long r0 = 0; r0 < MT; r0 += rows_chunk) {
    long nr = MT - r0; if (nr > rows_chunk) nr = rows_chunk;
    int nbm = (int)(nr / 256);
    k_packq<<<dim3((int)(nr / 64), 4), 256, 0, stream>>>(v + (size_t)r0 * 1024, vq, 1024);
    k_gemm<<<nbm * 8, 512, 49152, stream>>>(vq, wq, hp, vwgt, part, (int)(r0 / 256), nbm);
  }

  k_softmax<<<64, 256, 0, stream>>>(part, wt);
  k_ctx_f32<<<dim3(64, 16), 256, 0, stream>>>(v, wt, ctxp);
  k_out<<<64, 256, 0, stream>>>(ctxp, out);
}